// Round 18
// baseline (556.920 us; speedup 1.0000x reference)
//
#include <hip/hip_runtime.h>
#include <math.h>

typedef unsigned char u8;
typedef unsigned short u16;
typedef unsigned int u32;
typedef __attribute__((ext_vector_type(8))) short bf16x8;
typedef __attribute__((ext_vector_type(4))) float f32x4;

#define NE 30
static constexpr float QMAX  = 160.0f;
static constexpr float QS8   = 255.0f / QMAX;
static constexpr float HQS8  = 0.5f * QS8;
static constexpr float LOGA  = -8.3177661667193430f;   // -log(4096)
static constexpr float LOGB  = -7.6246189861593985f;   // -log(2048)
static constexpr float LOG2E = 1.4426950408889634f;
static constexpr float LN2   = 0.6931471805599453f;
static constexpr float LOGA2 = LOGA * LOG2E;
static constexpr float LOGB2 = LOGB * LOG2E;

// ---- ws layout (float units) ----
static constexpr size_t OFF_MT  = 1048576;   // Mt hi/lo u16[2*768*128]
static constexpr size_t OFF_N   = 1146880;   // norms[8192]
static constexpr size_t OFF_POT = 1155072;   // 2 dv x 16384
static constexpr size_t OFF_OUT = 1187840;   // 2 dv x 8192
static constexpr size_t OFF_CQ  = 1204224;   // u8 C area; also fp32 transform partials (16MB)
// u8-unit offsets inside CQ area:
static constexpr size_t CQ_YX = 8388608;     // Cyx after Cxy (4096*2048 u8)
static constexpr size_t CQ_YY = 16777216;    // Cyy after Cyx
static constexpr size_t CQ_DV = 20971520;    // per-dv stride (u8)

__device__ __forceinline__ float fexp2(float x) {
#if __has_builtin(__builtin_amdgcn_exp2f)
  return __builtin_amdgcn_exp2f(x);
#else
  return exp2f(x);
#endif
}
__device__ __forceinline__ float flog2(float x) {
#if __has_builtin(__builtin_amdgcn_logf)
  return __builtin_amdgcn_logf(x);
#else
  return __log2f(x);
#endif
}

// exact split x = hi + lo (both bf16-truncations)
__device__ __forceinline__ void split1(float x, u16& h, u16& l) {
  const u32 u = __float_as_uint(x);
  const u32 hb = u & 0xffff0000u;
  const float xl = x - __uint_as_float(hb);
  h = (u16)(hb >> 16);
  l = (u16)(__float_as_uint(xl) >> 16);
}

__device__ __forceinline__ void splitAB(const float4 p, const float4 q,
                                        bf16x8& h, bf16x8& l) {
  const float pf[8] = {p.x, p.y, p.z, p.w, q.x, q.y, q.z, q.w};
#pragma unroll
  for (int i = 0; i < 8; ++i) {
    u16 hh, ll;
    split1(pf[i], hh, ll);
    h[i] = (short)hh;
    l[i] = (short)ll;
  }
}

// ---------------- prep M ----------------
__global__ __launch_bounds__(256) void prep_m_kernel(
    const float* __restrict__ Mw, float* __restrict__ ws)
{
  const int id = blockIdx.x * 256 + threadIdx.x;
  const int ks = id >> 9;
  const int g  = (id >> 7) & 3;
  const int n  = id & 127;
  u16* mthi = (u16*)(ws + OFF_MT);
  u16* mtlo = mthi + 98304;
  bf16x8 h, l;
#pragma unroll
  for (int e = 0; e < 8; ++e) {
    const float x = Mw[(size_t)(ks * 32 + g * 8 + e) * 128 + n];
    u16 hh, ll;
    split1(x, hh, ll);
    h[e] = (short)hh;
    l[e] = (short)ll;
  }
  *reinterpret_cast<bf16x8*>(mthi + (size_t)id * 8) = h;
  *reinterpret_cast<bf16x8*>(mtlo + (size_t)id * 8) = l;
}

// ---------------- MFMA transform, split-K x4 ----------------
__global__ __launch_bounds__(256) void transform_kernel(
    const float* __restrict__ d, const float* __restrict__ s1,
    const float* __restrict__ s2, float* __restrict__ ws)
{
  const int tid = threadIdx.x;
  const int w = tid >> 6, ln = tid & 63;
  const int lr = ln & 15, lg = ln >> 4;
  const int tile = blockIdx.x & 127;
  const int ks4  = blockIdx.x >> 7;
  const float* Xb; int r0;
  if (tile < 64)      { Xb = d;  r0 = tile * 64; }
  else if (tile < 96) { Xb = s1; r0 = (tile - 64) * 64; }
  else                { Xb = s2; r0 = (tile - 96) * 64; }
  const int grow = tile * 64;
  const u16* mthi = (const u16*)(ws + OFF_MT);
  const u16* mtlo = mthi + 98304;

  f32x4 acc[8];
  const f32x4 zero = {0.f, 0.f, 0.f, 0.f};
#pragma unroll
  for (int nt = 0; nt < 8; ++nt) acc[nt] = zero;

#pragma unroll
  for (int ksl = 0; ksl < 6; ++ksl) {
    const int ks = ks4 * 6 + ksl;
    const float* xp = Xb + (size_t)(r0 + w * 16 + lr) * 768 + ks * 32 + lg * 8;
    const float4 p = *reinterpret_cast<const float4*>(xp);
    const float4 q = *reinterpret_cast<const float4*>(xp + 4);
    bf16x8 ah, al;
    splitAB(p, q, ah, al);
#pragma unroll
    for (int nt = 0; nt < 8; ++nt) {
      const size_t bo = ((size_t)(ks * 4 + lg) * 128 + nt * 16 + lr) * 8;
      const bf16x8 bh = *reinterpret_cast<const bf16x8*>(mthi + bo);
      const bf16x8 bl = *reinterpret_cast<const bf16x8*>(mtlo + bo);
      acc[nt] = __builtin_amdgcn_mfma_f32_16x16x32_bf16(ah, bh, acc[nt], 0, 0, 0);
      acc[nt] = __builtin_amdgcn_mfma_f32_16x16x32_bf16(ah, bl, acc[nt], 0, 0, 0);
      acc[nt] = __builtin_amdgcn_mfma_f32_16x16x32_bf16(al, bh, acc[nt], 0, 0, 0);
    }
  }
  float* P = ws + OFF_CQ + (size_t)ks4 * 1048576;
#pragma unroll
  for (int nt = 0; nt < 8; ++nt)
#pragma unroll
    for (int reg = 0; reg < 4; ++reg)
      P[(size_t)(grow + w * 16 + lg * 4 + reg) * 128 + nt * 16 + lr] = acc[nt][reg];
}

// ---------------- reduce 4 K-partials -> norms + hi/lo split T ----------------
__global__ __launch_bounds__(256) void reduceT_kernel(float* __restrict__ ws)
{
  const int wv = threadIdx.x >> 6, ln = threadIdx.x & 63;
  const int row = blockIdx.x * 4 + wv;
  const float2* Pb = reinterpret_cast<const float2*>(ws + OFF_CQ);
  const size_t idx = (size_t)row * 64 + ln;
  float2 t = Pb[idx];
  {
    const float2 b = Pb[idx + 524288];
    const float2 c = Pb[idx + 1048576];
    const float2 e = Pb[idx + 1572864];
    t.x += b.x + c.x + e.x;
    t.y += b.y + c.y + e.y;
  }
  float s = fmaf(t.x, t.x, t.y * t.y);
#pragma unroll
  for (int off = 32; off; off >>= 1) s += __shfl_xor(s, off);
  if (ln == 0) ws[OFF_N + row] = s;
  u16 h0, l0, h1, l1;
  split1(t.x, h0, l0);
  split1(t.y, h1, l1);
  u32* thiw = (u32*)ws;
  u32* tlow = thiw + 524288;
  thiw[idx] = (u32)h0 | ((u32)h1 << 16);
  tlow[idx] = (u32)l0 | ((u32)l1 << 16);
}

// ---------------- MFMA cost kernel: Cxy + Cyy only, 32x512 tiles, u8 output ----------------
// grid = 1536: per dv {Cxy 128x4, Cyy 64x4}
__global__ __launch_bounds__(256) void cost_all_kernel(float* __restrict__ ws)
{
  __shared__ __align__(16) float eb[16 * 516];
  const int tid = threadIdx.x;
  const int w = tid >> 6, ln = tid & 63;
  const int lr = ln & 15, lg = ln >> 4;

  const int b = blockIdx.x;
  const int dv = b / 768;
  const int bb = b - dv * 768;
  const u16* thi = (const u16*)ws;
  const u16* tlo = thi + 1048576;
  const u16* yhi = thi + (size_t)(4096 + dv * 2048) * 128;
  const u16* ylo = tlo + (size_t)(4096 + dv * 2048) * 128;
  const float* nrm = ws + OFF_N;
  u8* cq = (u8*)(ws + OFF_CQ) + (size_t)dv * CQ_DV;

  const u16 *xhi_, *xlo_, *yhi_, *ylo_;
  const float *nx, *ny;
  u8* C; int ldc, i0, j0;
  if (bb < 512) {            // Cxy
    i0 = (bb & 127) * 32; j0 = (bb >> 7) * 512;
    xhi_ = thi; xlo_ = tlo; yhi_ = yhi; ylo_ = ylo;
    nx = nrm; ny = nrm + 4096 + dv * 2048;
    C = cq; ldc = 2048;
  } else {                   // Cyy
    const int b2 = bb - 512;
    i0 = (b2 & 63) * 32; j0 = (b2 >> 6) * 512;
    xhi_ = yhi; xlo_ = ylo; yhi_ = yhi; ylo_ = ylo;
    nx = nrm + 4096 + dv * 2048; ny = nx;
    C = cq + CQ_YY; ldc = 2048;
  }
  const int cw = j0 + w * 128;

  f32x4 acc[2][8];
  const f32x4 zero = {0.f, 0.f, 0.f, 0.f};
#pragma unroll
  for (int mt = 0; mt < 2; ++mt)
#pragma unroll
    for (int nt = 0; nt < 8; ++nt) acc[mt][nt] = zero;

#pragma unroll
  for (int ks = 0; ks < 4; ++ks) {
    bf16x8 ah[2], al[2];
#pragma unroll
    for (int mt = 0; mt < 2; ++mt) {
      const size_t xo = (size_t)(i0 + mt * 16 + lr) * 128 + ks * 32 + lg * 8;
      ah[mt] = *reinterpret_cast<const bf16x8*>(xhi_ + xo);
      al[mt] = *reinterpret_cast<const bf16x8*>(xlo_ + xo);
    }
#pragma unroll
    for (int ntg = 0; ntg < 2; ++ntg) {
      bf16x8 bh[4], bl[4];
#pragma unroll
      for (int q = 0; q < 4; ++q) {
        const int nt = ntg * 4 + q;
        const size_t yo = (size_t)(cw + nt * 16 + lr) * 128 + ks * 32 + lg * 8;
        bh[q] = *reinterpret_cast<const bf16x8*>(yhi_ + yo);
        bl[q] = *reinterpret_cast<const bf16x8*>(ylo_ + yo);
      }
#pragma unroll
      for (int q = 0; q < 4; ++q) {
        const int nt = ntg * 4 + q;
#pragma unroll
        for (int mt = 0; mt < 2; ++mt) {
          acc[mt][nt] = __builtin_amdgcn_mfma_f32_16x16x32_bf16(ah[mt], bh[q], acc[mt][nt], 0, 0, 0);
          acc[mt][nt] = __builtin_amdgcn_mfma_f32_16x16x32_bf16(ah[mt], bl[q], acc[mt][nt], 0, 0, 0);
          acc[mt][nt] = __builtin_amdgcn_mfma_f32_16x16x32_bf16(al[mt], bh[q], acc[mt][nt], 0, 0, 0);
        }
      }
    }
  }

  float ct[8];
  {
    const float4 n0 = *reinterpret_cast<const float4*>(ny + j0 + ln * 8);
    const float4 n1 = *reinterpret_cast<const float4*>(ny + j0 + ln * 8 + 4);
    ct[0] = n0.x * HQS8; ct[1] = n0.y * HQS8; ct[2] = n0.z * HQS8; ct[3] = n0.w * HQS8;
    ct[4] = n1.x * HQS8; ct[5] = n1.y * HQS8; ct[6] = n1.z * HQS8; ct[7] = n1.w * HQS8;
  }

#pragma unroll
  for (int h = 0; h < 2; ++h) {
    if (h) __syncthreads();
#pragma unroll
    for (int nt = 0; nt < 8; ++nt)
#pragma unroll
      for (int reg = 0; reg < 4; ++reg)
        eb[(lg * 4 + reg) * 516 + w * 128 + nt * 16 + lr] = acc[h][nt][reg];
    __syncthreads();
#pragma unroll
    for (int rr = 0; rr < 4; ++rr) {
      const int rl = w * 4 + rr;
      const int rg = i0 + h * 16 + rl;
      const float rowt = fmaf(nx[rg], HQS8, 0.5f);
      const float* lp = eb + rl * 516 + ln * 8;
      const float4 e0 = *reinterpret_cast<const float4*>(lp);
      const float4 e1 = *reinterpret_cast<const float4*>(lp + 4);
      const float q0 = fmaxf(fminf(fmaf(e0.x, -QS8, ct[0] + rowt), 255.f), 0.f);
      const float q1 = fmaxf(fminf(fmaf(e0.y, -QS8, ct[1] + rowt), 255.f), 0.f);
      const float q2 = fmaxf(fminf(fmaf(e0.z, -QS8, ct[2] + rowt), 255.f), 0.f);
      const float q3 = fmaxf(fminf(fmaf(e0.w, -QS8, ct[3] + rowt), 255.f), 0.f);
      const float q4 = fmaxf(fminf(fmaf(e1.x, -QS8, ct[4] + rowt), 255.f), 0.f);
      const float q5 = fmaxf(fminf(fmaf(e1.y, -QS8, ct[5] + rowt), 255.f), 0.f);
      const float q6 = fmaxf(fminf(fmaf(e1.z, -QS8, ct[6] + rowt), 255.f), 0.f);
      const float q7 = fmaxf(fminf(fmaf(e1.w, -QS8, ct[7] + rowt), 255.f), 0.f);
      uint2 v;
      v.x = (u32)q0 | ((u32)q1 << 8) | ((u32)q2 << 16) | ((u32)q3 << 24);
      v.y = (u32)q4 | ((u32)q5 << 8) | ((u32)q6 << 16) | ((u32)q7 << 24);
      *reinterpret_cast<uint2*>(C + (size_t)rg * ldc + j0 + ln * 8) = v;
    }
  }
}

// ---------------- u8 transpose: Cyx[j][i] = Cxy[i][j], 128x128 byte tiles ----------------
// grid = 1024: 2 dv x 32 (i-tiles) x 16 (j-tiles)
__global__ __launch_bounds__(256) void transpose_c_kernel(float* __restrict__ ws)
{
  __shared__ u8 tb[128 * 132];
  const int b = blockIdx.x;
  const int dv = b >> 9;
  const int bi = (b >> 4) & 31;
  const int bj = b & 15;
  u8* cq = (u8*)(ws + OFF_CQ) + (size_t)dv * CQ_DV;
  const u8* src = cq;            // Cxy [4096][2048]
  u8* dst = cq + CQ_YX;          // Cyx [2048][4096]
  const int t = threadIdx.x;
  {
    const int ir = t >> 1, co = (t & 1) * 64;
    const u8* sp = src + (size_t)(bi * 128 + ir) * 2048 + bj * 128 + co;
    u8* lp = tb + ir * 132 + co;
#pragma unroll
    for (int k = 0; k < 4; ++k)
      *reinterpret_cast<uint4*>(lp + k * 16) =
          *reinterpret_cast<const uint4*>(sp + k * 16);
  }
  __syncthreads();
#pragma unroll
  for (int p = 0; p < 4; ++p) {
    const int jr = p * 32 + (t >> 3);
    const int ib = (t & 7) * 16;
    u32 wv[4];
#pragma unroll
    for (int q = 0; q < 4; ++q) {
      u32 x = (u32)tb[(ib + q * 4 + 0) * 132 + jr];
      x |= (u32)tb[(ib + q * 4 + 1) * 132 + jr] << 8;
      x |= (u32)tb[(ib + q * 4 + 2) * 132 + jr] << 16;
      x |= (u32)tb[(ib + q * 4 + 3) * 132 + jr] << 24;
      wv[q] = x;
    }
    uint4 v;
    v.x = wv[0]; v.y = wv[1]; v.z = wv[2]; v.w = wv[3];
    *reinterpret_cast<uint4*>(dst + (size_t)(bj * 128 + jr) * 4096 + bi * 128 + ib) = v;
  }
}

// ---------------- 2-row wave softmin on u8 C; h loaded once per 2 rows (r14 proven) ----------------
template <int NH>
__device__ __forceinline__ void softmin2(
    const u8* __restrict__ Cbase, const int ldc, const float* __restrict__ h,
    const float lw2, const float ie2, const float qie2, const float negeln2,
    const float* __restrict__ oldv, float* __restrict__ o,
    const int row0, const bool avg, const int ln)
{
  float m[2], s[2];
#pragma unroll
  for (int r = 0; r < 2; ++r) { m[r] = -3.0e38f; s[r] = 0.f; }
#pragma unroll
  for (int hf = 0; hf < NH; ++hf) {
    uint2 cq[2][4];
#pragma unroll
    for (int r = 0; r < 2; ++r) {
      const u8* cp = Cbase + (size_t)(row0 + r) * ldc + hf * 2048 + ln * 8;
#pragma unroll
      for (int k = 0; k < 4; ++k)
        cq[r][k] = *reinterpret_cast<const uint2*>(cp + k * 512);
    }
    const float* hp = h + hf * 2048 + ln * 8;
    float4 hv[8];
#pragma unroll
    for (int k = 0; k < 4; ++k) {
      hv[k * 2]     = *reinterpret_cast<const float4*>(hp + k * 512);
      hv[k * 2 + 1] = *reinterpret_cast<const float4*>(hp + k * 512 + 4);
    }
#pragma unroll
    for (int k = 0; k < 4; ++k) {
      float ht[8];
      ht[0] = fmaf(hv[k * 2].x, ie2, lw2);
      ht[1] = fmaf(hv[k * 2].y, ie2, lw2);
      ht[2] = fmaf(hv[k * 2].z, ie2, lw2);
      ht[3] = fmaf(hv[k * 2].w, ie2, lw2);
      ht[4] = fmaf(hv[k * 2 + 1].x, ie2, lw2);
      ht[5] = fmaf(hv[k * 2 + 1].y, ie2, lw2);
      ht[6] = fmaf(hv[k * 2 + 1].z, ie2, lw2);
      ht[7] = fmaf(hv[k * 2 + 1].w, ie2, lw2);
#pragma unroll
      for (int r = 0; r < 2; ++r) {
        const uint2 c = cq[r][k];
        const float a0 = ht[0] - (float)(c.x & 0xffu) * qie2;
        const float a1 = ht[1] - (float)((c.x >> 8) & 0xffu) * qie2;
        const float a2 = ht[2] - (float)((c.x >> 16) & 0xffu) * qie2;
        const float a3 = ht[3] - (float)(c.x >> 24) * qie2;
        const float a4 = ht[4] - (float)(c.y & 0xffu) * qie2;
        const float a5 = ht[5] - (float)((c.y >> 8) & 0xffu) * qie2;
        const float a6 = ht[6] - (float)((c.y >> 16) & 0xffu) * qie2;
        const float a7 = ht[7] - (float)(c.y >> 24) * qie2;
        const float cm = fmaxf(fmaxf(fmaxf(a0, a1), fmaxf(a2, a3)),
                               fmaxf(fmaxf(a4, a5), fmaxf(a6, a7)));
        const float nm = fmaxf(m[r], cm);
        float e = fexp2(a0 - nm);
        e += fexp2(a1 - nm);
        e += fexp2(a2 - nm);
        e += fexp2(a3 - nm);
        e += fexp2(a4 - nm);
        e += fexp2(a5 - nm);
        e += fexp2(a6 - nm);
        e += fexp2(a7 - nm);
        s[r] = fmaf(s[r], fexp2(m[r] - nm), e);
        m[r] = nm;
      }
    }
  }
#pragma unroll
  for (int r = 0; r < 2; ++r) {
#pragma unroll
    for (int off = 32; off; off >>= 1) {
      const float om = __shfl_xor(m[r], off);
      const float os = __shfl_xor(s[r], off);
      const float nm = fmaxf(m[r], om);
      s[r] = fmaf(s[r], fexp2(m[r] - nm), os * fexp2(om - nm));
      m[r] = nm;
    }
  }
  if (ln == 0) {
#pragma unroll
    for (int r = 0; r < 2; ++r) {
      float v = negeln2 * (m[r] + flog2(s[r]));
      if (avg) v = 0.5f * (oldv[row0 + r] + v);
      o[row0 + r] = v;
    }
  }
}

// one launch = one Sinkhorn iteration; 1024 blocks, each handles BOTH dv halves
// (block = {gt, ft, ft, gy} x 2 -> all blocks co-resident at 4/CU, zero tail)
__global__ __launch_bounds__(256, 6) void sinkhorn_iter_kernel(
    float* __restrict__ ws, const float ie2, const float negeln2, const float qie2,
    const int cur, const int fin)
{
  const int w = threadIdx.x >> 6, ln = threadIdx.x & 63;
  const int bb = blockIdx.x;   // 0..1023
#pragma unroll
  for (int dv = 0; dv < 2; ++dv) {
    float* pot  = ws + OFF_POT + dv * 16384;
    float* outv = ws + OFF_OUT + dv * 8192;
    const u8* cq = reinterpret_cast<const u8*>(ws + OFF_CQ) + (size_t)dv * CQ_DV;
    const float* fc = pot + cur * 4096;
    float* fn = pot + (cur ^ 1) * 4096;
    const float* gc = pot + 8192 + cur * 2048;
    float* gn = pot + 8192 + (cur ^ 1) * 2048;
    const float* yc = pot + 12288 + cur * 2048;
    float* yn = pot + 12288 + (cur ^ 1) * 2048;
    if (w == 0) {            // gt: 2 rows of Cyx (4096 cols), h = f
      softmin2<2>(cq + CQ_YX, 4096, fc, LOGA2, ie2, qie2, negeln2,
                  gc, fin ? (outv + 4096) : gn, bb * 2, !fin, ln);
    } else if (w == 3) {     // gy: 2 rows of Cyy, h = gy
      softmin2<1>(cq + CQ_YY, 2048, yc, LOGB2, ie2, qie2, negeln2,
                  yc, fin ? (outv + 6144) : yn, bb * 2, !fin, ln);
    } else {                 // ft: 2 rows of Cxy, h = g
      softmin2<1>(cq, 2048, gc, LOGB2, ie2, qie2, negeln2,
                  fc, fin ? outv : fn, bb * 4 + (w - 1) * 2, !fin, ln);
    }
  }
}

__global__ void init_pot_kernel(float* __restrict__ ws)
{
  const int i = blockIdx.x * 256 + threadIdx.x;
  if (i < 32768) ws[OFF_POT + i] = 0.f;
}

__global__ __launch_bounds__(256) void finalize_kernel(
    const float* __restrict__ ws, float* __restrict__ out)
{
  const float* ov = ws + OFF_OUT;
  const int tid = threadIdx.x;
  float v[6] = {0.f, 0.f, 0.f, 0.f, 0.f, 0.f};
  for (int i = tid; i < 4096; i += 256) { v[0] += ov[i]; v[3] += ov[8192 + i]; }
  for (int i = tid; i < 2048; i += 256) {
    v[1] += ov[4096 + i]; v[2] += ov[6144 + i];
    v[4] += ov[8192 + 4096 + i]; v[5] += ov[8192 + 6144 + i];
  }
  __shared__ float sh[6][4];
  const int wv = tid >> 6, ln = tid & 63;
#pragma unroll
  for (int q = 0; q < 6; ++q) {
    float s = v[q];
#pragma unroll
    for (int off = 32; off; off >>= 1) s += __shfl_xor(s, off);
    if (ln == 0) sh[q][wv] = s;
  }
  __syncthreads();
  if (tid == 0) {
    float t[6];
#pragma unroll
    for (int q = 0; q < 6; ++q) t[q] = sh[q][0] + sh[q][1] + sh[q][2] + sh[q][3];
    const float d1 = t[0] * (1.f / 4096.f) + (t[1] - t[2]) * (1.f / 2048.f);
    const float d2 = t[3] * (1.f / 4096.f) + (t[4] - t[5]) * (1.f / 2048.f);
    const float z = 0.1f * (d2 - d1);
    out[0] = 1.f / (1.f + expf(-z));
  }
}

extern "C" void kernel_launch(void* const* d_in, const int* in_sizes, int n_in,
                              void* d_out, int out_size, void* d_ws, size_t ws_size,
                              hipStream_t stream)
{
  const float* d  = (const float*)d_in[0];   // [4096][768]
  const float* s1 = (const float*)d_in[1];   // [2048][768]
  const float* s2 = (const float*)d_in[2];   // [2048][768]
  const float* Mw = (const float*)d_in[3];   // [768][128]
  float* out = (float*)d_out;
  float* ws = (float*)d_ws;

  float eps_l[NE];
  {
    double e = 1024.0;
    const double sc = 0.8 * 0.8;
    for (int k = 0; k < NE - 1; ++k) { eps_l[k] = (float)e; e *= sc; }
    eps_l[NE - 1] = (float)(0.05 * 0.05);
  }

  prep_m_kernel<<<48, 256, 0, stream>>>(Mw, ws);
  transform_kernel<<<512, 256, 0, stream>>>(d, s1, s2, ws);
  reduceT_kernel<<<2048, 256, 0, stream>>>(ws);

  cost_all_kernel<<<1536, 256, 0, stream>>>(ws);
  transpose_c_kernel<<<1024, 256, 0, stream>>>(ws);

  init_pot_kernel<<<128, 256, 0, stream>>>(ws);
  int cur = 0;
  for (int it = 0; it <= NE; ++it) {
    const int fin = (it == NE);
    const float e = eps_l[fin ? NE - 1 : it];
    const float ie2 = LOG2E / e;
    const float qie2 = (QMAX / 255.0f) * ie2;
    sinkhorn_iter_kernel<<<1024, 256, 0, stream>>>(ws, ie2, -e * LN2, qie2, cur, fin);
    if (!fin) cur ^= 1;
  }

  finalize_kernel<<<1, 256, 0, stream>>>(ws, out);
  (void)in_sizes; (void)n_in; (void)out_size; (void)ws_size;
}

// Round 19
// 484.430 us; speedup vs baseline: 1.1496x; 1.1496x over previous
//
#include <hip/hip_runtime.h>
#include <math.h>

typedef unsigned char u8;
typedef unsigned short u16;
typedef unsigned int u32;
typedef __attribute__((ext_vector_type(8))) short bf16x8;
typedef __attribute__((ext_vector_type(4))) float f32x4;

#define NE 30
static constexpr float QMAX  = 160.0f;
static constexpr float QS8   = 255.0f / QMAX;
static constexpr float HQS8  = 0.5f * QS8;
static constexpr float LOGA  = -8.3177661667193430f;   // -log(4096)
static constexpr float LOGB  = -7.6246189861593985f;   // -log(2048)
static constexpr float LOG2E = 1.4426950408889634f;
static constexpr float LN2   = 0.6931471805599453f;
static constexpr float LOGA2 = LOGA * LOG2E;
static constexpr float LOGB2 = LOGB * LOG2E;

// ---- ws layout (float units) ----
static constexpr size_t OFF_MT  = 1048576;   // Mt hi/lo u16[2*768*128]
static constexpr size_t OFF_N   = 1146880;   // norms[8192]
static constexpr size_t OFF_POT = 1155072;   // 2 dv x 16384
static constexpr size_t OFF_OUT = 1187840;   // 2 dv x 8192
static constexpr size_t OFF_CQ  = 1204224;   // u8 C area; also fp32 transform partials (16MB)
// u8-unit offsets inside CQ area:
static constexpr size_t CQ_YX = 8388608;     // Cyx after Cxy (4096*2048 u8)
static constexpr size_t CQ_YY = 16777216;    // Cyy after Cyx
static constexpr size_t CQ_DV = 20971520;    // per-dv stride (u8)

__device__ __forceinline__ float fexp2(float x) {
#if __has_builtin(__builtin_amdgcn_exp2f)
  return __builtin_amdgcn_exp2f(x);
#else
  return exp2f(x);
#endif
}
__device__ __forceinline__ float flog2(float x) {
#if __has_builtin(__builtin_amdgcn_logf)
  return __builtin_amdgcn_logf(x);
#else
  return __log2f(x);
#endif
}

// exact split x = hi + lo (both bf16-truncations)
__device__ __forceinline__ void split1(float x, u16& h, u16& l) {
  const u32 u = __float_as_uint(x);
  const u32 hb = u & 0xffff0000u;
  const float xl = x - __uint_as_float(hb);
  h = (u16)(hb >> 16);
  l = (u16)(__float_as_uint(xl) >> 16);
}

__device__ __forceinline__ void splitAB(const float4 p, const float4 q,
                                        bf16x8& h, bf16x8& l) {
  const float pf[8] = {p.x, p.y, p.z, p.w, q.x, q.y, q.z, q.w};
#pragma unroll
  for (int i = 0; i < 8; ++i) {
    u16 hh, ll;
    split1(pf[i], hh, ll);
    h[i] = (short)hh;
    l[i] = (short)ll;
  }
}

// ---------------- prep M ----------------
__global__ __launch_bounds__(256) void prep_m_kernel(
    const float* __restrict__ Mw, float* __restrict__ ws)
{
  const int id = blockIdx.x * 256 + threadIdx.x;
  const int ks = id >> 9;
  const int g  = (id >> 7) & 3;
  const int n  = id & 127;
  u16* mthi = (u16*)(ws + OFF_MT);
  u16* mtlo = mthi + 98304;
  bf16x8 h, l;
#pragma unroll
  for (int e = 0; e < 8; ++e) {
    const float x = Mw[(size_t)(ks * 32 + g * 8 + e) * 128 + n];
    u16 hh, ll;
    split1(x, hh, ll);
    h[e] = (short)hh;
    l[e] = (short)ll;
  }
  *reinterpret_cast<bf16x8*>(mthi + (size_t)id * 8) = h;
  *reinterpret_cast<bf16x8*>(mtlo + (size_t)id * 8) = l;
}

// ---------------- MFMA transform, split-K x4 ----------------
__global__ __launch_bounds__(256) void transform_kernel(
    const float* __restrict__ d, const float* __restrict__ s1,
    const float* __restrict__ s2, float* __restrict__ ws)
{
  const int tid = threadIdx.x;
  const int w = tid >> 6, ln = tid & 63;
  const int lr = ln & 15, lg = ln >> 4;
  const int tile = blockIdx.x & 127;
  const int ks4  = blockIdx.x >> 7;
  const float* Xb; int r0;
  if (tile < 64)      { Xb = d;  r0 = tile * 64; }
  else if (tile < 96) { Xb = s1; r0 = (tile - 64) * 64; }
  else                { Xb = s2; r0 = (tile - 96) * 64; }
  const int grow = tile * 64;
  const u16* mthi = (const u16*)(ws + OFF_MT);
  const u16* mtlo = mthi + 98304;

  f32x4 acc[8];
  const f32x4 zero = {0.f, 0.f, 0.f, 0.f};
#pragma unroll
  for (int nt = 0; nt < 8; ++nt) acc[nt] = zero;

#pragma unroll
  for (int ksl = 0; ksl < 6; ++ksl) {
    const int ks = ks4 * 6 + ksl;
    const float* xp = Xb + (size_t)(r0 + w * 16 + lr) * 768 + ks * 32 + lg * 8;
    const float4 p = *reinterpret_cast<const float4*>(xp);
    const float4 q = *reinterpret_cast<const float4*>(xp + 4);
    bf16x8 ah, al;
    splitAB(p, q, ah, al);
#pragma unroll
    for (int nt = 0; nt < 8; ++nt) {
      const size_t bo = ((size_t)(ks * 4 + lg) * 128 + nt * 16 + lr) * 8;
      const bf16x8 bh = *reinterpret_cast<const bf16x8*>(mthi + bo);
      const bf16x8 bl = *reinterpret_cast<const bf16x8*>(mtlo + bo);
      acc[nt] = __builtin_amdgcn_mfma_f32_16x16x32_bf16(ah, bh, acc[nt], 0, 0, 0);
      acc[nt] = __builtin_amdgcn_mfma_f32_16x16x32_bf16(ah, bl, acc[nt], 0, 0, 0);
      acc[nt] = __builtin_amdgcn_mfma_f32_16x16x32_bf16(al, bh, acc[nt], 0, 0, 0);
    }
  }
  float* P = ws + OFF_CQ + (size_t)ks4 * 1048576;
#pragma unroll
  for (int nt = 0; nt < 8; ++nt)
#pragma unroll
    for (int reg = 0; reg < 4; ++reg)
      P[(size_t)(grow + w * 16 + lg * 4 + reg) * 128 + nt * 16 + lr] = acc[nt][reg];
}

// ---------------- reduce 4 K-partials -> norms + hi/lo split T ----------------
__global__ __launch_bounds__(256) void reduceT_kernel(float* __restrict__ ws)
{
  const int wv = threadIdx.x >> 6, ln = threadIdx.x & 63;
  const int row = blockIdx.x * 4 + wv;
  const float2* Pb = reinterpret_cast<const float2*>(ws + OFF_CQ);
  const size_t idx = (size_t)row * 64 + ln;
  float2 t = Pb[idx];
  {
    const float2 b = Pb[idx + 524288];
    const float2 c = Pb[idx + 1048576];
    const float2 e = Pb[idx + 1572864];
    t.x += b.x + c.x + e.x;
    t.y += b.y + c.y + e.y;
  }
  float s = fmaf(t.x, t.x, t.y * t.y);
#pragma unroll
  for (int off = 32; off; off >>= 1) s += __shfl_xor(s, off);
  if (ln == 0) ws[OFF_N + row] = s;
  u16 h0, l0, h1, l1;
  split1(t.x, h0, l0);
  split1(t.y, h1, l1);
  u32* thiw = (u32*)ws;
  u32* tlow = thiw + 524288;
  thiw[idx] = (u32)h0 | ((u32)h1 << 16);
  tlow[idx] = (u32)l0 | ((u32)l1 << 16);
}

// ---------------- MFMA cost kernel: Cxy + Cyy only, 32x512 tiles, u8 output ----------------
// grid = 1536: per dv {Cxy 128x4, Cyy 64x4}
__global__ __launch_bounds__(256) void cost_all_kernel(float* __restrict__ ws)
{
  __shared__ __align__(16) float eb[16 * 516];
  const int tid = threadIdx.x;
  const int w = tid >> 6, ln = tid & 63;
  const int lr = ln & 15, lg = ln >> 4;

  const int b = blockIdx.x;
  const int dv = b / 768;
  const int bb = b - dv * 768;
  const u16* thi = (const u16*)ws;
  const u16* tlo = thi + 1048576;
  const u16* yhi = thi + (size_t)(4096 + dv * 2048) * 128;
  const u16* ylo = tlo + (size_t)(4096 + dv * 2048) * 128;
  const float* nrm = ws + OFF_N;
  u8* cq = (u8*)(ws + OFF_CQ) + (size_t)dv * CQ_DV;

  const u16 *xhi_, *xlo_, *yhi_, *ylo_;
  const float *nx, *ny;
  u8* C; int ldc, i0, j0;
  if (bb < 512) {            // Cxy
    i0 = (bb & 127) * 32; j0 = (bb >> 7) * 512;
    xhi_ = thi; xlo_ = tlo; yhi_ = yhi; ylo_ = ylo;
    nx = nrm; ny = nrm + 4096 + dv * 2048;
    C = cq; ldc = 2048;
  } else {                   // Cyy
    const int b2 = bb - 512;
    i0 = (b2 & 63) * 32; j0 = (b2 >> 6) * 512;
    xhi_ = yhi; xlo_ = ylo; yhi_ = yhi; ylo_ = ylo;
    nx = nrm + 4096 + dv * 2048; ny = nx;
    C = cq + CQ_YY; ldc = 2048;
  }
  const int cw = j0 + w * 128;

  f32x4 acc[2][8];
  const f32x4 zero = {0.f, 0.f, 0.f, 0.f};
#pragma unroll
  for (int mt = 0; mt < 2; ++mt)
#pragma unroll
    for (int nt = 0; nt < 8; ++nt) acc[mt][nt] = zero;

#pragma unroll
  for (int ks = 0; ks < 4; ++ks) {
    bf16x8 ah[2], al[2];
#pragma unroll
    for (int mt = 0; mt < 2; ++mt) {
      const size_t xo = (size_t)(i0 + mt * 16 + lr) * 128 + ks * 32 + lg * 8;
      ah[mt] = *reinterpret_cast<const bf16x8*>(xhi_ + xo);
      al[mt] = *reinterpret_cast<const bf16x8*>(xlo_ + xo);
    }
#pragma unroll
    for (int ntg = 0; ntg < 2; ++ntg) {
      bf16x8 bh[4], bl[4];
#pragma unroll
      for (int q = 0; q < 4; ++q) {
        const int nt = ntg * 4 + q;
        const size_t yo = (size_t)(cw + nt * 16 + lr) * 128 + ks * 32 + lg * 8;
        bh[q] = *reinterpret_cast<const bf16x8*>(yhi_ + yo);
        bl[q] = *reinterpret_cast<const bf16x8*>(ylo_ + yo);
      }
#pragma unroll
      for (int q = 0; q < 4; ++q) {
        const int nt = ntg * 4 + q;
#pragma unroll
        for (int mt = 0; mt < 2; ++mt) {
          acc[mt][nt] = __builtin_amdgcn_mfma_f32_16x16x32_bf16(ah[mt], bh[q], acc[mt][nt], 0, 0, 0);
          acc[mt][nt] = __builtin_amdgcn_mfma_f32_16x16x32_bf16(ah[mt], bl[q], acc[mt][nt], 0, 0, 0);
          acc[mt][nt] = __builtin_amdgcn_mfma_f32_16x16x32_bf16(al[mt], bh[q], acc[mt][nt], 0, 0, 0);
        }
      }
    }
  }

  float ct[8];
  {
    const float4 n0 = *reinterpret_cast<const float4*>(ny + j0 + ln * 8);
    const float4 n1 = *reinterpret_cast<const float4*>(ny + j0 + ln * 8 + 4);
    ct[0] = n0.x * HQS8; ct[1] = n0.y * HQS8; ct[2] = n0.z * HQS8; ct[3] = n0.w * HQS8;
    ct[4] = n1.x * HQS8; ct[5] = n1.y * HQS8; ct[6] = n1.z * HQS8; ct[7] = n1.w * HQS8;
  }

#pragma unroll
  for (int h = 0; h < 2; ++h) {
    if (h) __syncthreads();
#pragma unroll
    for (int nt = 0; nt < 8; ++nt)
#pragma unroll
      for (int reg = 0; reg < 4; ++reg)
        eb[(lg * 4 + reg) * 516 + w * 128 + nt * 16 + lr] = acc[h][nt][reg];
    __syncthreads();
#pragma unroll
    for (int rr = 0; rr < 4; ++rr) {
      const int rl = w * 4 + rr;
      const int rg = i0 + h * 16 + rl;
      const float rowt = fmaf(nx[rg], HQS8, 0.5f);
      const float* lp = eb + rl * 516 + ln * 8;
      const float4 e0 = *reinterpret_cast<const float4*>(lp);
      const float4 e1 = *reinterpret_cast<const float4*>(lp + 4);
      const float q0 = fmaxf(fminf(fmaf(e0.x, -QS8, ct[0] + rowt), 255.f), 0.f);
      const float q1 = fmaxf(fminf(fmaf(e0.y, -QS8, ct[1] + rowt), 255.f), 0.f);
      const float q2 = fmaxf(fminf(fmaf(e0.z, -QS8, ct[2] + rowt), 255.f), 0.f);
      const float q3 = fmaxf(fminf(fmaf(e0.w, -QS8, ct[3] + rowt), 255.f), 0.f);
      const float q4 = fmaxf(fminf(fmaf(e1.x, -QS8, ct[4] + rowt), 255.f), 0.f);
      const float q5 = fmaxf(fminf(fmaf(e1.y, -QS8, ct[5] + rowt), 255.f), 0.f);
      const float q6 = fmaxf(fminf(fmaf(e1.z, -QS8, ct[6] + rowt), 255.f), 0.f);
      const float q7 = fmaxf(fminf(fmaf(e1.w, -QS8, ct[7] + rowt), 255.f), 0.f);
      uint2 v;
      v.x = (u32)q0 | ((u32)q1 << 8) | ((u32)q2 << 16) | ((u32)q3 << 24);
      v.y = (u32)q4 | ((u32)q5 << 8) | ((u32)q6 << 16) | ((u32)q7 << 24);
      *reinterpret_cast<uint2*>(C + (size_t)rg * ldc + j0 + ln * 8) = v;
    }
  }
}

// ---------------- u8 transpose: Cyx[j][i] = Cxy[i][j], 128x128 byte tiles ----------------
// grid = 1024: 2 dv x 32 (i-tiles) x 16 (j-tiles)
__global__ __launch_bounds__(256) void transpose_c_kernel(float* __restrict__ ws)
{
  __shared__ u8 tb[128 * 132];
  const int b = blockIdx.x;
  const int dv = b >> 9;
  const int bi = (b >> 4) & 31;
  const int bj = b & 15;
  u8* cq = (u8*)(ws + OFF_CQ) + (size_t)dv * CQ_DV;
  const u8* src = cq;            // Cxy [4096][2048]
  u8* dst = cq + CQ_YX;          // Cyx [2048][4096]
  const int t = threadIdx.x;
  {
    const int ir = t >> 1, co = (t & 1) * 64;
    const u8* sp = src + (size_t)(bi * 128 + ir) * 2048 + bj * 128 + co;
    u8* lp = tb + ir * 132 + co;
#pragma unroll
    for (int k = 0; k < 4; ++k)
      *reinterpret_cast<uint4*>(lp + k * 16) =
          *reinterpret_cast<const uint4*>(sp + k * 16);
  }
  __syncthreads();
#pragma unroll
  for (int p = 0; p < 4; ++p) {
    const int jr = p * 32 + (t >> 3);
    const int ib = (t & 7) * 16;
    u32 wv[4];
#pragma unroll
    for (int q = 0; q < 4; ++q) {
      u32 x = (u32)tb[(ib + q * 4 + 0) * 132 + jr];
      x |= (u32)tb[(ib + q * 4 + 1) * 132 + jr] << 8;
      x |= (u32)tb[(ib + q * 4 + 2) * 132 + jr] << 16;
      x |= (u32)tb[(ib + q * 4 + 3) * 132 + jr] << 24;
      wv[q] = x;
    }
    uint4 v;
    v.x = wv[0]; v.y = wv[1]; v.z = wv[2]; v.w = wv[3];
    *reinterpret_cast<uint4*>(dst + (size_t)(bj * 128 + jr) * 4096 + bi * 128 + ib) = v;
  }
}

// ---------------- 2-row wave softmin on u8 C; h loaded once per 2 rows (r14 proven) ----------------
template <int NH>
__device__ __forceinline__ void softmin2(
    const u8* __restrict__ Cbase, const int ldc, const float* __restrict__ h,
    const float lw2, const float ie2, const float qie2, const float negeln2,
    const float* __restrict__ oldv, float* __restrict__ o,
    const int row0, const bool avg, const int ln)
{
  float m[2], s[2];
#pragma unroll
  for (int r = 0; r < 2; ++r) { m[r] = -3.0e38f; s[r] = 0.f; }
#pragma unroll
  for (int hf = 0; hf < NH; ++hf) {
    uint2 cq[2][4];
#pragma unroll
    for (int r = 0; r < 2; ++r) {
      const u8* cp = Cbase + (size_t)(row0 + r) * ldc + hf * 2048 + ln * 8;
#pragma unroll
      for (int k = 0; k < 4; ++k)
        cq[r][k] = *reinterpret_cast<const uint2*>(cp + k * 512);
    }
    const float* hp = h + hf * 2048 + ln * 8;
    float4 hv[8];
#pragma unroll
    for (int k = 0; k < 4; ++k) {
      hv[k * 2]     = *reinterpret_cast<const float4*>(hp + k * 512);
      hv[k * 2 + 1] = *reinterpret_cast<const float4*>(hp + k * 512 + 4);
    }
#pragma unroll
    for (int k = 0; k < 4; ++k) {
      float ht[8];
      ht[0] = fmaf(hv[k * 2].x, ie2, lw2);
      ht[1] = fmaf(hv[k * 2].y, ie2, lw2);
      ht[2] = fmaf(hv[k * 2].z, ie2, lw2);
      ht[3] = fmaf(hv[k * 2].w, ie2, lw2);
      ht[4] = fmaf(hv[k * 2 + 1].x, ie2, lw2);
      ht[5] = fmaf(hv[k * 2 + 1].y, ie2, lw2);
      ht[6] = fmaf(hv[k * 2 + 1].z, ie2, lw2);
      ht[7] = fmaf(hv[k * 2 + 1].w, ie2, lw2);
#pragma unroll
      for (int r = 0; r < 2; ++r) {
        const uint2 c = cq[r][k];
        const float a0 = ht[0] - (float)(c.x & 0xffu) * qie2;
        const float a1 = ht[1] - (float)((c.x >> 8) & 0xffu) * qie2;
        const float a2 = ht[2] - (float)((c.x >> 16) & 0xffu) * qie2;
        const float a3 = ht[3] - (float)(c.x >> 24) * qie2;
        const float a4 = ht[4] - (float)(c.y & 0xffu) * qie2;
        const float a5 = ht[5] - (float)((c.y >> 8) & 0xffu) * qie2;
        const float a6 = ht[6] - (float)((c.y >> 16) & 0xffu) * qie2;
        const float a7 = ht[7] - (float)(c.y >> 24) * qie2;
        const float cm = fmaxf(fmaxf(fmaxf(a0, a1), fmaxf(a2, a3)),
                               fmaxf(fmaxf(a4, a5), fmaxf(a6, a7)));
        const float nm = fmaxf(m[r], cm);
        float e = fexp2(a0 - nm);
        e += fexp2(a1 - nm);
        e += fexp2(a2 - nm);
        e += fexp2(a3 - nm);
        e += fexp2(a4 - nm);
        e += fexp2(a5 - nm);
        e += fexp2(a6 - nm);
        e += fexp2(a7 - nm);
        s[r] = fmaf(s[r], fexp2(m[r] - nm), e);
        m[r] = nm;
      }
    }
  }
#pragma unroll
  for (int r = 0; r < 2; ++r) {
#pragma unroll
    for (int off = 32; off; off >>= 1) {
      const float om = __shfl_xor(m[r], off);
      const float os = __shfl_xor(s[r], off);
      const float nm = fmaxf(m[r], om);
      s[r] = fmaf(s[r], fexp2(m[r] - nm), os * fexp2(om - nm));
      m[r] = nm;
    }
  }
  if (ln == 0) {
#pragma unroll
    for (int r = 0; r < 2; ++r) {
      float v = negeln2 * (m[r] + flog2(s[r]));
      if (avg) v = 0.5f * (oldv[row0 + r] + v);
      o[row0 + r] = v;
    }
  }
}

// one launch = one Sinkhorn iteration; 2048 blocks, each block = {gt, ft, ft, gy} (r14 proven)
__global__ __launch_bounds__(256, 6) void sinkhorn_iter_kernel(
    float* __restrict__ ws, const float ie2, const float negeln2, const float qie2,
    const int cur, const int fin)
{
  const int w = threadIdx.x >> 6, ln = threadIdx.x & 63;
  const int dv = blockIdx.x >> 10;
  const int bb = blockIdx.x & 1023;
  float* pot  = ws + OFF_POT + dv * 16384;
  float* outv = ws + OFF_OUT + dv * 8192;
  const u8* cq = reinterpret_cast<const u8*>(ws + OFF_CQ) + (size_t)dv * CQ_DV;
  const float* fc = pot + cur * 4096;
  float* fn = pot + (cur ^ 1) * 4096;
  const float* gc = pot + 8192 + cur * 2048;
  float* gn = pot + 8192 + (cur ^ 1) * 2048;
  const float* yc = pot + 12288 + cur * 2048;
  float* yn = pot + 12288 + (cur ^ 1) * 2048;
  if (w == 0) {            // gt: 2 rows of Cyx (4096 cols), h = f
    softmin2<2>(cq + CQ_YX, 4096, fc, LOGA2, ie2, qie2, negeln2,
                gc, fin ? (outv + 4096) : gn, bb * 2, !fin, ln);
  } else if (w == 3) {     // gy: 2 rows of Cyy, h = gy
    softmin2<1>(cq + CQ_YY, 2048, yc, LOGB2, ie2, qie2, negeln2,
                yc, fin ? (outv + 6144) : yn, bb * 2, !fin, ln);
  } else {                 // ft: 2 rows of Cxy, h = g
    softmin2<1>(cq, 2048, gc, LOGB2, ie2, qie2, negeln2,
                fc, fin ? outv : fn, bb * 4 + (w - 1) * 2, !fin, ln);
  }
}

__global__ void init_pot_kernel(float* __restrict__ ws)
{
  const int i = blockIdx.x * 256 + threadIdx.x;
  if (i < 32768) ws[OFF_POT + i] = 0.f;
}

__global__ __launch_bounds__(256) void finalize_kernel(
    const float* __restrict__ ws, float* __restrict__ out)
{
  const float* ov = ws + OFF_OUT;
  const int tid = threadIdx.x;
  float v[6] = {0.f, 0.f, 0.f, 0.f, 0.f, 0.f};
  for (int i = tid; i < 4096; i += 256) { v[0] += ov[i]; v[3] += ov[8192 + i]; }
  for (int i = tid; i < 2048; i += 256) {
    v[1] += ov[4096 + i]; v[2] += ov[6144 + i];
    v[4] += ov[8192 + 4096 + i]; v[5] += ov[8192 + 6144 + i];
  }
  __shared__ float sh[6][4];
  const int wv = tid >> 6, ln = tid & 63;
#pragma unroll
  for (int q = 0; q < 6; ++q) {
    float s = v[q];
#pragma unroll
    for (int off = 32; off; off >>= 1) s += __shfl_xor(s, off);
    if (ln == 0) sh[q][wv] = s;
  }
  __syncthreads();
  if (tid == 0) {
    float t[6];
#pragma unroll
    for (int q = 0; q < 6; ++q) t[q] = sh[q][0] + sh[q][1] + sh[q][2] + sh[q][3];
    const float d1 = t[0] * (1.f / 4096.f) + (t[1] - t[2]) * (1.f / 2048.f);
    const float d2 = t[3] * (1.f / 4096.f) + (t[4] - t[5]) * (1.f / 2048.f);
    const float z = 0.1f * (d2 - d1);
    out[0] = 1.f / (1.f + expf(-z));
  }
}

extern "C" void kernel_launch(void* const* d_in, const int* in_sizes, int n_in,
                              void* d_out, int out_size, void* d_ws, size_t ws_size,
                              hipStream_t stream)
{
  const float* d  = (const float*)d_in[0];   // [4096][768]
  const float* s1 = (const float*)d_in[1];   // [2048][768]
  const float* s2 = (const float*)d_in[2];   // [2048][768]
  const float* Mw = (const float*)d_in[3];   // [768][128]
  float* out = (float*)d_out;
  float* ws = (float*)d_ws;

  float eps_l[NE];
  {
    double e = 1024.0;
    const double sc = 0.8 * 0.8;
    for (int k = 0; k < NE - 1; ++k) { eps_l[k] = (float)e; e *= sc; }
    eps_l[NE - 1] = (float)(0.05 * 0.05);
  }

  prep_m_kernel<<<48, 256, 0, stream>>>(Mw, ws);
  transform_kernel<<<512, 256, 0, stream>>>(d, s1, s2, ws);
  reduceT_kernel<<<2048, 256, 0, stream>>>(ws);

  cost_all_kernel<<<1536, 256, 0, stream>>>(ws);
  transpose_c_kernel<<<1024, 256, 0, stream>>>(ws);

  init_pot_kernel<<<128, 256, 0, stream>>>(ws);
  int cur = 0;
  for (int it = 0; it <= NE; ++it) {
    const int fin = (it == NE);
    const float e = eps_l[fin ? NE - 1 : it];
    const float ie2 = LOG2E / e;
    const float qie2 = (QMAX / 255.0f) * ie2;
    sinkhorn_iter_kernel<<<2048, 256, 0, stream>>>(ws, ie2, -e * LN2, qie2, cur, fin);
    if (!fin) cur ^= 1;
  }

  finalize_kernel<<<1, 256, 0, stream>>>(ws, out);
  (void)in_sizes; (void)n_in; (void)out_size; (void)ws_size;
}